// Round 5
// baseline (559.936 us; speedup 1.0000x reference)
//
#include <hip/hip_runtime.h>
#include <hip/hip_bf16.h>

// LSTM: S=128, N=2048, H=128, O=128. fp32 buffers, bf16 MFMA internally.
// 128 persistent blocks x 512 threads; block b owns samples [16b,16b+16).
// R5 = R4 theory (x path off LDS), risk-reduced implementation:
//   All 8 waves need the SAME A-tile (A-frags are wave-invariant), so LDS
//   reads were 8x-amplified (64 b128/step/CU ~ 770cy serialized LDS service
//   between dependent barriers = the convoy; R3 phase-stagger was neutral
//   because both orders burst on the same LDS unit). Each lane now
//   global-loads its xg A-frag directly (L1-cached: 8 waves hit the same
//   8KB tile) and converts to bf16 in-register with plain f2b (no inline
//   asm; R4's cvt_pk asm + 250+ VGPR peak produced NaN).
//   LDS holds only the h double-buffer (2 x 16 x HP shorts = 8.5 KB).
//   - per-step barrier: lgkmcnt(0)-only + raw s_barrier (R1: vmcnt drain
//     off the critical path; keep global loads/stores in flight)
//   - x_{s+1} loads issued at step top (8 named float4s), consumed after
//     the h-MFMA block -> ~600cy of latency hiding, regs freed at convert

#define S_LEN   128
#define N_BATCH 2048
#define H_DIM   128
#define O_DIM   128

using short8  = __attribute__((ext_vector_type(8))) short;  // 8 bf16 (4 VGPRs)
using floatx4 = __attribute__((ext_vector_type(4))) float;  // 4 fp32 acc
typedef unsigned short u16;

#define HP   136                  // h row pitch in shorts: 272B = 17*16 (b128-aligned),
                                  // row->row bank shift 4 => exactly-uniform 8 words/bank
#define HBUF (16 * HP)            // one h buffer: 16 rows x 128 cols (+pad)

__device__ __forceinline__ u16 f2b(float f) {   // RNE f32->bf16
    unsigned int u = __float_as_uint(f);
    return (u16)((u + 0x7FFF + ((u >> 16) & 1)) >> 16);
}
__device__ __forceinline__ short8 pack8(const float* p) {
    short8 r;
#pragma unroll
    for (int i = 0; i < 8; ++i) r[i] = (short)f2b(p[i]);
    return r;
}
__device__ __forceinline__ short8 cvt8(float4 a, float4 b) {  // two float4 -> 8 bf16
    short8 r;
    r[0] = (short)f2b(a.x); r[1] = (short)f2b(a.y);
    r[2] = (short)f2b(a.z); r[3] = (short)f2b(a.w);
    r[4] = (short)f2b(b.x); r[5] = (short)f2b(b.y);
    r[6] = (short)f2b(b.z); r[7] = (short)f2b(b.w);
    return r;
}
__device__ __forceinline__ float sigmoidf_fast(float v) {
    return __builtin_amdgcn_rcpf(1.0f + __builtin_amdgcn_exp2f(-1.4426950408889634f * v));
}
__device__ __forceinline__ float tanhf_fast(float v) {
    return 1.0f - 2.0f * __builtin_amdgcn_rcpf(1.0f + __builtin_amdgcn_exp2f(2.8853900817779268f * v));
}

// lgkmcnt-only barrier: LDS writes/reads ordered, global loads/stores stay in flight.
__device__ __forceinline__ void lds_barrier() {
    asm volatile("s_waitcnt lgkmcnt(0)" ::: "memory");
    __builtin_amdgcn_s_barrier();
}

__global__ __launch_bounds__(512, 2)
void lstm_persist(const float* __restrict__ x,
                  const float* __restrict__ W_ih,
                  const float* __restrict__ W_hh,
                  const float* __restrict__ b_ih,
                  const float* __restrict__ b_hh,
                  const float* __restrict__ W_out,
                  const float* __restrict__ b_out,
                  float* __restrict__ pred) {
    __shared__ short sh[2 * HBUF];

    const int tid  = (int)threadIdx.x;
    const int wave = tid >> 6;           // 0..7
    const int lane = tid & 63;
    const int quad = lane >> 4;          // 0..3
    const int l15  = lane & 15;
    const int n0   = (int)blockIdx.x * 16;

    // ---- weights into bf16 register fragments ----
    // B-frag (16x16x32): lane holds B[k=quad*8+j][n=l15].
    // wave w owns gate j-slice [w*16,w*16+16): wx = W_ih, wh = W_hh.
    short8 wx[4][4], wh[4][4], wo[4];
    float  biasv[4];
#pragma unroll
    for (int t = 0; t < 4; ++t) {
        const int g = t * 128 + wave * 16 + l15;
#pragma unroll
        for (int kk = 0; kk < 4; ++kk) {
            wx[t][kk] = pack8(W_ih + g * H_DIM + kk * 32 + quad * 8);
            wh[t][kk] = pack8(W_hh + g * H_DIM + kk * 32 + quad * 8);
        }
        biasv[t] = b_ih[g] + b_hh[g];
    }
    const int ocol = wave * 16 + l15;
#pragma unroll
    for (int kk = 0; kk < 4; ++kk)
        wo[kk] = pack8(W_out + ocol * H_DIM + kk * 32 + quad * 8);
    const float bo = b_out[ocol];

    // per-lane xg A-frag source: row (n0+l15), cols quad*8 + kk*32 + 0..7
    const float*  xb    = x + (size_t)(n0 + l15) * H_DIM + quad * 8;
    const size_t  xstep = (size_t)N_BATCH * H_DIM;

    // ---- prologue: zero h buf0 (h_{-1} = 0) ----
    for (int i = tid; i < 16 * 128; i += 512)
        sh[(i >> 7) * HP + (i & 127)] = 0;

    // x_0 frags -> xg_0 (no LDS involved)
    floatx4 xg0 = {biasv[0], biasv[0], biasv[0], biasv[0]};
    floatx4 xg1 = {biasv[1], biasv[1], biasv[1], biasv[1]};
    floatx4 xg2 = {biasv[2], biasv[2], biasv[2], biasv[2]};
    floatx4 xg3 = {biasv[3], biasv[3], biasv[3], biasv[3]};
#pragma unroll
    for (int kk = 0; kk < 4; ++kk) {
        float4 a = *reinterpret_cast<const float4*>(xb + kk * 32);
        float4 b = *reinterpret_cast<const float4*>(xb + kk * 32 + 4);
        short8 xf = cvt8(a, b);
        xg0 = __builtin_amdgcn_mfma_f32_16x16x32_bf16(xf, wx[0][kk], xg0, 0, 0, 0);
        xg1 = __builtin_amdgcn_mfma_f32_16x16x32_bf16(xf, wx[1][kk], xg1, 0, 0, 0);
        xg2 = __builtin_amdgcn_mfma_f32_16x16x32_bf16(xf, wx[2][kk], xg2, 0, 0, 0);
        xg3 = __builtin_amdgcn_mfma_f32_16x16x32_bf16(xf, wx[3][kk], xg3, 0, 0, 0);
    }
    __syncthreads();   // h buf0 zeros visible

    float cc[4] = {0.f, 0.f, 0.f, 0.f};  // cell: c[m=quad*4+r][j=wave*16+l15]
    const int arow = l15 * HP + quad * 8; // A-frag base: A[m=l15][k=quad*8+..]
    const int hcol = wave * 16 + l15;

    // ---- main recurrence. buf[s&1] holds h_{s-1}; buf[(s&1)^1] receives h_s. ----
    for (int s = 0; s < S_LEN; ++s) {
        short* shb = sh + (s & 1) * HBUF;
        short* shn = sh + ((s & 1) ^ 1) * HBUF;
        const bool   ldx = (s < S_LEN - 1);
        const float* xs1 = xb + (size_t)(s + 1) * xstep;   // x_{s+1}

        // gate accs seeded by pipelined xg_s; ao = out-proj of h_{s-1}
        floatx4 g0 = xg0, g1 = xg1, g2 = xg2, g3 = xg3;
        floatx4 ao = {bo, bo, bo, bo};

        // issue x_{s+1} frag loads now; consumed after the h-MFMA block
        float4 xr0, xr1, xr2, xr3, xr4, xr5, xr6, xr7;
        if (ldx) {
            xr0 = *reinterpret_cast<const float4*>(xs1 + 0);
            xr1 = *reinterpret_cast<const float4*>(xs1 + 4);
            xr2 = *reinterpret_cast<const float4*>(xs1 + 32);
            xr3 = *reinterpret_cast<const float4*>(xs1 + 36);
            xr4 = *reinterpret_cast<const float4*>(xs1 + 64);
            xr5 = *reinterpret_cast<const float4*>(xs1 + 68);
            xr6 = *reinterpret_cast<const float4*>(xs1 + 96);
            xr7 = *reinterpret_cast<const float4*>(xs1 + 100);
        }

        // ---- critical path: h_{s-1} MFMA (K=128, 4-deep chains) ----
#pragma unroll
        for (int kk = 0; kk < 4; ++kk) {
            short8 ah = *reinterpret_cast<const short8*>(&shb[arow + kk * 32]);
            g0 = __builtin_amdgcn_mfma_f32_16x16x32_bf16(ah, wh[0][kk], g0, 0, 0, 0);
            g1 = __builtin_amdgcn_mfma_f32_16x16x32_bf16(ah, wh[1][kk], g1, 0, 0, 0);
            g2 = __builtin_amdgcn_mfma_f32_16x16x32_bf16(ah, wh[2][kk], g2, 0, 0, 0);
            g3 = __builtin_amdgcn_mfma_f32_16x16x32_bf16(ah, wh[3][kk], g3, 0, 0, 0);
            ao = __builtin_amdgcn_mfma_f32_16x16x32_bf16(ah, wo[kk], ao, 0, 0, 0);
        }

        // pred_{s-1}: issue early, drain overlaps the rest of the step
        if (s > 0) {
            size_t base = ((size_t)(s - 1) * N_BATCH + n0 + quad * 4) * O_DIM + wave * 16 + l15;
#pragma unroll
            for (int r = 0; r < 4; ++r)
                pred[base + (size_t)r * O_DIM] = ao[r];
        }

        // ---- off-path: xg_{s+1} from register frags (NO LDS), skipped at s=127 ----
        if (ldx) {
            short8 xf0 = cvt8(xr0, xr1);
            short8 xf1 = cvt8(xr2, xr3);
            short8 xf2 = cvt8(xr4, xr5);
            short8 xf3 = cvt8(xr6, xr7);
            xg0 = floatx4{biasv[0], biasv[0], biasv[0], biasv[0]};
            xg1 = floatx4{biasv[1], biasv[1], biasv[1], biasv[1]};
            xg2 = floatx4{biasv[2], biasv[2], biasv[2], biasv[2]};
            xg3 = floatx4{biasv[3], biasv[3], biasv[3], biasv[3]};
            xg0 = __builtin_amdgcn_mfma_f32_16x16x32_bf16(xf0, wx[0][0], xg0, 0, 0, 0);
            xg1 = __builtin_amdgcn_mfma_f32_16x16x32_bf16(xf0, wx[1][0], xg1, 0, 0, 0);
            xg2 = __builtin_amdgcn_mfma_f32_16x16x32_bf16(xf0, wx[2][0], xg2, 0, 0, 0);
            xg3 = __builtin_amdgcn_mfma_f32_16x16x32_bf16(xf0, wx[3][0], xg3, 0, 0, 0);
            xg0 = __builtin_amdgcn_mfma_f32_16x16x32_bf16(xf1, wx[0][1], xg0, 0, 0, 0);
            xg1 = __builtin_amdgcn_mfma_f32_16x16x32_bf16(xf1, wx[1][1], xg1, 0, 0, 0);
            xg2 = __builtin_amdgcn_mfma_f32_16x16x32_bf16(xf1, wx[2][1], xg2, 0, 0, 0);
            xg3 = __builtin_amdgcn_mfma_f32_16x16x32_bf16(xf1, wx[3][1], xg3, 0, 0, 0);
            xg0 = __builtin_amdgcn_mfma_f32_16x16x32_bf16(xf2, wx[0][2], xg0, 0, 0, 0);
            xg1 = __builtin_amdgcn_mfma_f32_16x16x32_bf16(xf2, wx[1][2], xg1, 0, 0, 0);
            xg2 = __builtin_amdgcn_mfma_f32_16x16x32_bf16(xf2, wx[2][2], xg2, 0, 0, 0);
            xg3 = __builtin_amdgcn_mfma_f32_16x16x32_bf16(xf2, wx[3][2], xg3, 0, 0, 0);
            xg0 = __builtin_amdgcn_mfma_f32_16x16x32_bf16(xf3, wx[0][3], xg0, 0, 0, 0);
            xg1 = __builtin_amdgcn_mfma_f32_16x16x32_bf16(xf3, wx[1][3], xg1, 0, 0, 0);
            xg2 = __builtin_amdgcn_mfma_f32_16x16x32_bf16(xf3, wx[2][3], xg2, 0, 0, 0);
            xg3 = __builtin_amdgcn_mfma_f32_16x16x32_bf16(xf3, wx[3][3], xg3, 0, 0, 0);
        }

        // ---- activations + state update (D: row m=quad*4+r, col j=wave*16+l15) ----
        float hv[4];
#pragma unroll
        for (int r = 0; r < 4; ++r) {
            float iv = sigmoidf_fast(g0[r]);
            float fv = sigmoidf_fast(g1[r]);
            float gv = tanhf_fast(g2[r]);
            float ov = sigmoidf_fast(g3[r]);
            cc[r] = fv * cc[r] + iv * gv;
            hv[r] = ov * tanhf_fast(cc[r]);
        }
#pragma unroll
        for (int r = 0; r < 4; ++r)
            shn[(quad * 4 + r) * HP + hcol] = (short)f2b(hv[r]);

        lds_barrier();   // lgkmcnt(0)-only: keep global loads/stores in flight
    }

    // ---- epilogue: pred_{S-1} from h_127 in buf0 ----
    floatx4 ao = {bo, bo, bo, bo};
#pragma unroll
    for (int kk = 0; kk < 4; ++kk) {
        short8 ah = *reinterpret_cast<const short8*>(&sh[arow + kk * 32]);
        ao = __builtin_amdgcn_mfma_f32_16x16x32_bf16(ah, wo[kk], ao, 0, 0, 0);
    }
    size_t base = ((size_t)(S_LEN - 1) * N_BATCH + n0 + quad * 4) * O_DIM + wave * 16 + l15;
#pragma unroll
    for (int r = 0; r < 4; ++r)
        pred[base + (size_t)r * O_DIM] = ao[r];
}

extern "C" void kernel_launch(void* const* d_in, const int* in_sizes, int n_in,
                              void* d_out, int out_size, void* d_ws, size_t ws_size,
                              hipStream_t stream) {
    const float* x    = (const float*)d_in[0];
    const float* Wih  = (const float*)d_in[1];
    const float* Whh  = (const float*)d_in[2];
    const float* bih  = (const float*)d_in[3];
    const float* bhh  = (const float*)d_in[4];
    const float* Wout = (const float*)d_in[5];
    const float* bout = (const float*)d_in[6];
    float* pred = (float*)d_out;

    lstm_persist<<<dim3(N_BATCH / 16), dim3(512), 0, stream>>>(
        x, Wih, Whh, bih, bhh, Wout, bout, pred);
}

// Round 6
// 344.947 us; speedup vs baseline: 1.6233x; 1.6233x over previous
//
#include <hip/hip_runtime.h>
#include <hip/hip_bf16.h>

// LSTM: S=128, N=2048, H=128, O=128. fp32 buffers, bf16 MFMA internally.
// 128 persistent blocks x 512 threads; block b owns samples [16b,16b+16).
// R6 = R1 structure (verified 211us) + VALU-issue cuts:
//   * 2-step unroll with xgA/xgB accumulator role swap: h-MFMA accumulates
//     directly into the xg seed registers (no 16-mov g=xg copy).
//   * log2e scale factors folded into bf16 weights/biases at load time
//     (i,f,o rows x -1.4427; g rows x +2.8854) -> sigmoid = rcp(1+exp2(z)),
//     tanh_g = 1-2*rcp(1+exp2(z)): saves the per-element scale muls.
//   * incremental pred / x pointers (no per-step 64-bit recompute).
// R5 lesson (404us): per-lane A-frag global loads are transpose-shaped
// (16 lines/instr through L1) - the x8 LDS A-frag amplification IS the
// efficient redistribution path. Keep x staging through LDS.
// R1 lesson: vmcnt drain at barrier is off the critical path; keep the
// lgkmcnt-only barrier anyway (harmless).

#define S_LEN   128
#define N_BATCH 2048
#define H_DIM   128
#define O_DIM   128

using short8  = __attribute__((ext_vector_type(8))) short;  // 8 bf16 (4 VGPRs)
using short4v = __attribute__((ext_vector_type(4))) short;  // 4 bf16
using floatx4 = __attribute__((ext_vector_type(4))) float;  // 4 fp32 acc
typedef unsigned short u16;

#define ROWP     264                 // LDS row pitch in bf16 elems (256 + 8 pad)
#define BUFELEMS (16 * ROWP)         // one tile buffer: 16 rows x [x(0:128)|h(128:256)]

__device__ __forceinline__ u16 f2b(float f) {   // RNE f32->bf16
    unsigned int u = __float_as_uint(f);
    return (u16)((u + 0x7FFF + ((u >> 16) & 1)) >> 16);
}
__device__ __forceinline__ short8 pack8s(const float* p, float k) {  // scaled pack
    short8 r;
#pragma unroll
    for (int i = 0; i < 8; ++i) r[i] = (short)f2b(k * p[i]);
    return r;
}
__device__ __forceinline__ short4v pack4(float4 f) {
    short4v r;
    r[0] = (short)f2b(f.x); r[1] = (short)f2b(f.y);
    r[2] = (short)f2b(f.z); r[3] = (short)f2b(f.w);
    return r;
}
__device__ __forceinline__ float tanhf_fast(float v) {   // for tanh(c): unscaled input
    return 1.0f - 2.0f * __builtin_amdgcn_rcpf(1.0f + __builtin_amdgcn_exp2f(2.8853900817779268f * v));
}

// lgkmcnt-only barrier: LDS writes/reads ordered, global loads/stores stay in flight.
__device__ __forceinline__ void lds_barrier() {
    asm volatile("s_waitcnt lgkmcnt(0)" ::: "memory");
    __builtin_amdgcn_s_barrier();
}

// One recurrence step. g0..g3 enter holding xg_s (scaled, bias-seeded) and are
// accumulated into gates; n0..n3 receive xg_{s+1}. All control flags are
// wave-uniform SALU branches.
__device__ __forceinline__ void step_body(
    int s,
    floatx4& g0, floatx4& g1, floatx4& g2, floatx4& g3,
    floatx4& n0v, floatx4& n1v, floatx4& n2v, floatx4& n3v,
    const short* shb, short* shn, short* stagep,
    const short8 (&wh)[4][4], const short8 (&wx)[4][4], const short8 (&wo)[4],
    const float (&biasv)[4], float bo,
    float (&cc)[4], float4& xcur, const float*& xptr, float*& pcur,
    int arow, int hcol, int qrow)
{
    floatx4 ao = {bo, bo, bo, bo};

    // ---- critical path: h_{s-1} MFMA (K=128, 4-deep chains into xg seeds) ----
#pragma unroll
    for (int kk = 0; kk < 4; ++kk) {
        short8 ah = *reinterpret_cast<const short8*>(&shb[arow + 128 + kk * 32]);
        g0 = __builtin_amdgcn_mfma_f32_16x16x32_bf16(ah, wh[0][kk], g0, 0, 0, 0);
        g1 = __builtin_amdgcn_mfma_f32_16x16x32_bf16(ah, wh[1][kk], g1, 0, 0, 0);
        g2 = __builtin_amdgcn_mfma_f32_16x16x32_bf16(ah, wh[2][kk], g2, 0, 0, 0);
        g3 = __builtin_amdgcn_mfma_f32_16x16x32_bf16(ah, wh[3][kk], g3, 0, 0, 0);
        ao = __builtin_amdgcn_mfma_f32_16x16x32_bf16(ah, wo[kk], ao, 0, 0, 0);
    }

    // pred_{s-1}: issue early so the store drain overlaps the rest of the step
    if (s > 0) {
#pragma unroll
        for (int r = 0; r < 4; ++r)
            pcur[(size_t)r * O_DIM] = ao[r];
        pcur += (size_t)N_BATCH * O_DIM;
    }

    // ---- off-path: xg_{s+1} from x-region of B_s ----
    if (s < S_LEN - 1) {
        n0v = floatx4{biasv[0], biasv[0], biasv[0], biasv[0]};
        n1v = floatx4{biasv[1], biasv[1], biasv[1], biasv[1]};
        n2v = floatx4{biasv[2], biasv[2], biasv[2], biasv[2]};
        n3v = floatx4{biasv[3], biasv[3], biasv[3], biasv[3]};
#pragma unroll
        for (int kk = 0; kk < 4; ++kk) {
            short8 axv = *reinterpret_cast<const short8*>(&shb[arow + kk * 32]);
            n0v = __builtin_amdgcn_mfma_f32_16x16x32_bf16(axv, wx[0][kk], n0v, 0, 0, 0);
            n1v = __builtin_amdgcn_mfma_f32_16x16x32_bf16(axv, wx[1][kk], n1v, 0, 0, 0);
            n2v = __builtin_amdgcn_mfma_f32_16x16x32_bf16(axv, wx[2][kk], n2v, 0, 0, 0);
            n3v = __builtin_amdgcn_mfma_f32_16x16x32_bf16(axv, wx[3][kk], n3v, 0, 0, 0);
        }
    }

    // stage x_{s+2} into B_{s+1}; then refill xcur with x_{s+3}
    if (s <= S_LEN - 3)
        *reinterpret_cast<short4v*>(stagep) = pack4(xcur);
    if (s <= S_LEN - 4)
        xcur = *reinterpret_cast<const float4*>(xptr);
    xptr += (size_t)N_BATCH * H_DIM;

    // ---- activations + state update (row m=qrow+r, col j=hcol-128) ----
    // gates pre-scaled: i,f,o by -log2e, g by +2*log2e (folded into weights)
#pragma unroll
    for (int r = 0; r < 4; ++r) {
        float iv = __builtin_amdgcn_rcpf(1.0f + __builtin_amdgcn_exp2f(g0[r]));
        float fv = __builtin_amdgcn_rcpf(1.0f + __builtin_amdgcn_exp2f(g1[r]));
        float gv = 1.0f - 2.0f * __builtin_amdgcn_rcpf(1.0f + __builtin_amdgcn_exp2f(g2[r]));
        float ov = __builtin_amdgcn_rcpf(1.0f + __builtin_amdgcn_exp2f(g3[r]));
        cc[r] = fv * cc[r] + iv * gv;
        shn[(qrow + r) * ROWP + hcol] = (short)f2b(ov * tanhf_fast(cc[r]));
    }

    lds_barrier();   // lgkmcnt(0)-only: keep global loads/stores in flight
}

__global__ __launch_bounds__(512, 2)
void lstm_persist(const float* __restrict__ x,
                  const float* __restrict__ W_ih,
                  const float* __restrict__ W_hh,
                  const float* __restrict__ b_ih,
                  const float* __restrict__ b_hh,
                  const float* __restrict__ W_out,
                  const float* __restrict__ b_out,
                  float* __restrict__ pred) {
    __shared__ short sh[2 * BUFELEMS];

    const int tid  = (int)threadIdx.x;
    const int wave = tid >> 6;           // 0..7
    const int lane = tid & 63;
    const int quad = lane >> 4;          // 0..3
    const int l15  = lane & 15;
    const int n0   = (int)blockIdx.x * 16;

    const float kSig = -1.4426950408889634f;   // i,f,o rows: sigmoid scale
    const float kG   =  2.8853900817779268f;   // g rows: tanh scale

    // ---- weights into bf16 register fragments (scale factors folded in) ----
    // B-frag (16x16x32): lane holds B[k=quad*8+j][n=l15].
    // wave w owns gate j-slice [w*16,w*16+16): wx = W_ih, wh = W_hh.
    short8 wx[4][4], wh[4][4], wo[4];
    float  biasv[4];
#pragma unroll
    for (int t = 0; t < 4; ++t) {
        const float sc = (t == 2) ? kG : kSig;
        const int g = t * 128 + wave * 16 + l15;
#pragma unroll
        for (int kk = 0; kk < 4; ++kk) {
            wx[t][kk] = pack8s(W_ih + g * H_DIM + kk * 32 + quad * 8, sc);
            wh[t][kk] = pack8s(W_hh + g * H_DIM + kk * 32 + quad * 8, sc);
        }
        biasv[t] = sc * (b_ih[g] + b_hh[g]);
    }
    const int ocol = wave * 16 + l15;
#pragma unroll
    for (int kk = 0; kk < 4; ++kk)
        wo[kk] = pack8s(W_out + ocol * H_DIM + kk * 32 + quad * 8, 1.0f);
    const float bo = b_out[ocol];

    // x loader: all 512 threads, one float4 each (16 rows x 128 cols)
    const int xm = tid >> 5;             // row 0..15
    const int xq = (tid & 31) * 4;       // col 0..124 step 4

    // ---- prologue ----
    // zero h region of buf0 (h_{-1} = 0)
    for (int i = tid; i < 16 * 128; i += 512)
        sh[(i >> 7) * ROWP + 128 + (i & 127)] = 0;
    {   // stage x_0 -> buf1 x-region (for xg_0), x_1 -> buf0 x-region (for xg_1 at step 0)
        float4 f0 = *reinterpret_cast<const float4*>(x + ((size_t)(n0 + xm)) * H_DIM + xq);
        float4 f1 = *reinterpret_cast<const float4*>(x + ((size_t)N_BATCH + n0 + xm) * H_DIM + xq);
        *reinterpret_cast<short4v*>(&sh[BUFELEMS + xm * ROWP + xq]) = pack4(f0);
        *reinterpret_cast<short4v*>(&sh[xm * ROWP + xq]) = pack4(f1);
    }
    // register prefetch: xcur = x_2 (staged during step 0)
    float4 xcur = *reinterpret_cast<const float4*>(x + ((size_t)2 * N_BATCH + n0 + xm) * H_DIM + xq);
    __syncthreads();

    const int arow = l15 * ROWP + quad * 8;   // A-frag base: A[m=l15][k=quad*8+..]
    const int hcol = 128 + wave * 16 + l15;
    const int qrow = quad * 4;

    // xg_0 from buf1 x-region -> xgA
    floatx4 xgA0 = {biasv[0], biasv[0], biasv[0], biasv[0]};
    floatx4 xgA1 = {biasv[1], biasv[1], biasv[1], biasv[1]};
    floatx4 xgA2 = {biasv[2], biasv[2], biasv[2], biasv[2]};
    floatx4 xgA3 = {biasv[3], biasv[3], biasv[3], biasv[3]};
#pragma unroll
    for (int kk = 0; kk < 4; ++kk) {
        short8 a = *reinterpret_cast<const short8*>(&sh[BUFELEMS + arow + kk * 32]);
        xgA0 = __builtin_amdgcn_mfma_f32_16x16x32_bf16(a, wx[0][kk], xgA0, 0, 0, 0);
        xgA1 = __builtin_amdgcn_mfma_f32_16x16x32_bf16(a, wx[1][kk], xgA1, 0, 0, 0);
        xgA2 = __builtin_amdgcn_mfma_f32_16x16x32_bf16(a, wx[2][kk], xgA2, 0, 0, 0);
        xgA3 = __builtin_amdgcn_mfma_f32_16x16x32_bf16(a, wx[3][kk], xgA3, 0, 0, 0);
    }
    __syncthreads();   // buf1-x reads done before step 0 stages x_2 there

    floatx4 xgB0, xgB1, xgB2, xgB3;      // odd-step xg set (built in even bodies)
    float cc[4] = {0.f, 0.f, 0.f, 0.f};  // cell: c[m=qrow+r][j=wave*16+l15]

    short* const sA = sh;                    // buf0
    short* const sB = sh + BUFELEMS;         // buf1
    short* const stageA = &sA[xm * ROWP + xq];
    short* const stageB = &sB[xm * ROWP + xq];

    // incremental pointers
    const float* xptr = x + (size_t)3 * N_BATCH * H_DIM + ((size_t)(n0 + xm)) * H_DIM + xq;
    float*       pcur = pred + ((size_t)(n0 + qrow)) * O_DIM + wave * 16 + l15;

    // ---- main recurrence, 2-step unrolled with xgA/xgB role swap ----
    // B_s = buf[s&1] holds [x_{s+1} | h_{s-1}].
    for (int it = 0; it < S_LEN / 2; ++it) {
        step_body(2 * it,     xgA0, xgA1, xgA2, xgA3, xgB0, xgB1, xgB2, xgB3,
                  sA, sB, stageB, wh, wx, wo, biasv, bo, cc, xcur, xptr, pcur,
                  arow, hcol, qrow);
        step_body(2 * it + 1, xgB0, xgB1, xgB2, xgB3, xgA0, xgA1, xgA2, xgA3,
                  sB, sA, stageA, wh, wx, wo, biasv, bo, cc, xcur, xptr, pcur,
                  arow, hcol, qrow);
    }

    // ---- epilogue: pred_{S-1} from h_127 in buf0 ----
    floatx4 ao = {bo, bo, bo, bo};
#pragma unroll
    for (int kk = 0; kk < 4; ++kk) {
        short8 ah = *reinterpret_cast<const short8*>(&sh[arow + 128 + kk * 32]);
        ao = __builtin_amdgcn_mfma_f32_16x16x32_bf16(ah, wo[kk], ao, 0, 0, 0);
    }
#pragma unroll
    for (int r = 0; r < 4; ++r)
        pcur[(size_t)r * O_DIM] = ao[r];
}

extern "C" void kernel_launch(void* const* d_in, const int* in_sizes, int n_in,
                              void* d_out, int out_size, void* d_ws, size_t ws_size,
                              hipStream_t stream) {
    const float* x    = (const float*)d_in[0];
    const float* Wih  = (const float*)d_in[1];
    const float* Whh  = (const float*)d_in[2];
    const float* bih  = (const float*)d_in[3];
    const float* bhh  = (const float*)d_in[4];
    const float* Wout = (const float*)d_in[5];
    const float* bout = (const float*)d_in[6];
    float* pred = (float*)d_out;

    lstm_persist<<<dim3(N_BATCH / 16), dim3(512), 0, stream>>>(
        x, Wih, Whh, bih, bhh, Wout, bout, pred);
}